// Round 2
// baseline (4596.056 us; speedup 1.0000x reference)
//
#include <hip/hip_runtime.h>

// LSTMForecaster: B=2048, S=512, IN=1, H=64, OUT=72, 2 LSTM layers + FC.
// Fused persistent kernel, round 2: K-split across lane pairs.
//  - 512 threads/block (8 waves/CU = 2 waves/SIMD) for latency hiding.
//  - thread t: gate g=t>>1, K-half kh=t&1 -> only 96 weight floats/thread,
//    fits the 256-VGPR budget so weights stay register-resident.
//  - pair partial sums combined with __shfl_xor(acc,1) (intra-wave).
//  - state update: exactly one (b,hid) state per thread.

#define BATCH 2048
#define SEQ   512
#define HIDN  64
#define GATES 256   // 4*H
#define NOUT  72
#define BT    8     // batch rows per block
#define NT    512   // threads per block

__device__ __forceinline__ float fast_rcp(float x) { return __builtin_amdgcn_rcpf(x); }
__device__ __forceinline__ float sigm(float x)   { return fast_rcp(1.f + __expf(-x)); }
__device__ __forceinline__ float tanh_f(float x) { return 1.f - 2.f * fast_rcp(__expf(2.f * x) + 1.f); }

__global__ __launch_bounds__(NT, 2)
void lstm2_fused_kernel(const float* __restrict__ x,     // [B,S,1]
                        const float* __restrict__ wih0,  // [256,1]
                        const float* __restrict__ whh0,  // [256,64]
                        const float* __restrict__ bih0,  // [256]
                        const float* __restrict__ bhh0,  // [256]
                        const float* __restrict__ wih1,  // [256,64]
                        const float* __restrict__ whh1,  // [256,64]
                        const float* __restrict__ bih1,  // [256]
                        const float* __restrict__ bhh1,  // [256]
                        const float* __restrict__ fcw,   // [72,64]
                        const float* __restrict__ fcb,   // [72]
                        float* __restrict__ out)         // [B,72]
{
    const int t  = threadIdx.x;
    const int g  = t >> 1;        // gate unit 0..255
    const int kh = t & 1;         // K-half 0/1
    const int ko = kh * 32;       // k offset
    const int b0 = blockIdx.x * BT;

    __shared__ float x_lds[BT][SEQ];     // 16 KB
    __shared__ float h0_lds[BT][HIDN];   // 2 KB
    __shared__ float h1_lds[BT][HIDN];   // 2 KB
    __shared__ float g_lds[BT][GATES];   // 8 KB

    // ---- 96 weight floats per thread, register-resident ----
    float w0[32], wi1[32], wh1[32];
    #pragma unroll
    for (int j = 0; j < 8; ++j) {
        *(float4*)&w0[j*4]  = *(const float4*)&whh0[g * HIDN + ko + j*4];
        *(float4*)&wi1[j*4] = *(const float4*)&wih1[g * HIDN + ko + j*4];
        *(float4*)&wh1[j*4] = *(const float4*)&whh1[g * HIDN + ko + j*4];
    }
    const float wx0 = wih0[g];
    const float bs0 = bih0[g] + bhh0[g];
    const float bs1 = bih1[g] + bhh1[g];

    // ---- stage x; zero states ----
    for (int i = t; i < BT * SEQ; i += NT) {
        int b = i >> 9, s = i & (SEQ - 1);
        x_lds[b][s] = x[(size_t)(b0 + b) * SEQ + s];
    }
    // NT == BT*HIDN == 512: one state element per thread
    const int sb = t >> 6;   // state batch row
    const int sh = t & 63;   // state hidden idx
    h0_lds[sb][sh] = 0.f;
    h1_lds[sb][sh] = 0.f;
    float c0 = 0.f, c1 = 0.f;

    const bool tanh_gate = (g >= 128) && (g < 192);   // waves 4,5 -> uniform
    const int  bb = kh * 4;   // which 4 batch rows this thread finalizes

    __syncthreads();

    #pragma unroll 1
    for (int s = 0; s < SEQ; ++s) {
        float acc[BT];

        // ======== phase A: layer-0 gates: bs0 + x*wih0 + h0 @ Whh0^T ========
        {
            float xv[BT];
            #pragma unroll
            for (int b = 0; b < BT; ++b) xv[b] = x_lds[b][s];
            #pragma unroll
            for (int b = 0; b < BT; ++b) acc[b] = kh ? (wx0 * xv[b]) : bs0;
        }
        #pragma unroll
        for (int k4 = 0; k4 < 8; ++k4) {
            #pragma unroll
            for (int b = 0; b < BT; ++b) {
                float4 h = *(const float4*)&h0_lds[b][ko + k4 * 4];
                acc[b] = fmaf(h.x, w0[k4*4+0], acc[b]);
                acc[b] = fmaf(h.y, w0[k4*4+1], acc[b]);
                acc[b] = fmaf(h.z, w0[k4*4+2], acc[b]);
                acc[b] = fmaf(h.w, w0[k4*4+3], acc[b]);
            }
        }
        #pragma unroll
        for (int b = 0; b < BT; ++b) acc[b] += __shfl_xor(acc[b], 1);
        if (tanh_gate) {
            #pragma unroll
            for (int j = 0; j < 4; ++j) g_lds[bb + j][g] = tanh_f(acc[bb + j]);
        } else {
            #pragma unroll
            for (int j = 0; j < 4; ++j) g_lds[bb + j][g] = sigm(acc[bb + j]);
        }
        __syncthreads();

        // ======== phase B: layer-0 state update (1 state/thread) ========
        {
            float i_ = g_lds[sb][sh],        f_ = g_lds[sb][64 + sh];
            float gg = g_lds[sb][128 + sh],  o_ = g_lds[sb][192 + sh];
            c0 = fmaf(f_, c0, i_ * gg);
            h0_lds[sb][sh] = o_ * tanh_f(c0);
        }
        __syncthreads();

        // ======== phase C: layer-1 gates: bs1 + h0new@Wih1^T + h1@Whh1^T ====
        #pragma unroll
        for (int b = 0; b < BT; ++b) acc[b] = kh ? 0.f : bs1;
        #pragma unroll
        for (int k4 = 0; k4 < 8; ++k4) {
            #pragma unroll
            for (int b = 0; b < BT; ++b) {
                float4 h = *(const float4*)&h0_lds[b][ko + k4 * 4];
                acc[b] = fmaf(h.x, wi1[k4*4+0], acc[b]);
                acc[b] = fmaf(h.y, wi1[k4*4+1], acc[b]);
                acc[b] = fmaf(h.z, wi1[k4*4+2], acc[b]);
                acc[b] = fmaf(h.w, wi1[k4*4+3], acc[b]);
            }
        }
        #pragma unroll
        for (int k4 = 0; k4 < 8; ++k4) {
            #pragma unroll
            for (int b = 0; b < BT; ++b) {
                float4 h = *(const float4*)&h1_lds[b][ko + k4 * 4];
                acc[b] = fmaf(h.x, wh1[k4*4+0], acc[b]);
                acc[b] = fmaf(h.y, wh1[k4*4+1], acc[b]);
                acc[b] = fmaf(h.z, wh1[k4*4+2], acc[b]);
                acc[b] = fmaf(h.w, wh1[k4*4+3], acc[b]);
            }
        }
        #pragma unroll
        for (int b = 0; b < BT; ++b) acc[b] += __shfl_xor(acc[b], 1);
        if (tanh_gate) {
            #pragma unroll
            for (int j = 0; j < 4; ++j) g_lds[bb + j][g] = tanh_f(acc[bb + j]);
        } else {
            #pragma unroll
            for (int j = 0; j < 4; ++j) g_lds[bb + j][g] = sigm(acc[bb + j]);
        }
        __syncthreads();

        // ======== phase D: layer-1 state update (1 state/thread) ========
        {
            float i_ = g_lds[sb][sh],        f_ = g_lds[sb][64 + sh];
            float gg = g_lds[sb][128 + sh],  o_ = g_lds[sb][192 + sh];
            c1 = fmaf(f_, c1, i_ * gg);
            h1_lds[sb][sh] = o_ * tanh_f(c1);
        }
        __syncthreads();   // also orders phase-D g_lds reads vs next phase-A writes
    }

    // ======== FC: out = h1[S-1] @ fc_w^T + fc_b ========
    for (int idx = t; idx < BT * NOUT; idx += NT) {
        int b = idx / NOUT, o = idx - b * NOUT;
        float a = fcb[o];
        #pragma unroll
        for (int k = 0; k < HIDN; ++k) a = fmaf(h1_lds[b][k], fcw[o * HIDN + k], a);
        out[(size_t)(b0 + b) * NOUT + o] = a;
    }
}

extern "C" void kernel_launch(void* const* d_in, const int* in_sizes, int n_in,
                              void* d_out, int out_size, void* d_ws, size_t ws_size,
                              hipStream_t stream) {
    const float* x    = (const float*)d_in[0];
    const float* wih0 = (const float*)d_in[1];
    const float* whh0 = (const float*)d_in[2];
    const float* bih0 = (const float*)d_in[3];
    const float* bhh0 = (const float*)d_in[4];
    const float* wih1 = (const float*)d_in[5];
    const float* whh1 = (const float*)d_in[6];
    const float* bih1 = (const float*)d_in[7];
    const float* bhh1 = (const float*)d_in[8];
    const float* fcw  = (const float*)d_in[9];
    const float* fcb  = (const float*)d_in[10];
    float* out = (float*)d_out;

    dim3 grid(BATCH / BT);   // 256 blocks -> 1 per CU
    dim3 block(NT);
    hipLaunchKernelGGL(lstm2_fused_kernel, grid, block, 0, stream,
                       x, wih0, whh0, bih0, bhh0, wih1, whh1, bih1, bhh1,
                       fcw, fcb, out);
}

// Round 3
// 830.246 us; speedup vs baseline: 5.5358x; 5.5358x over previous
//
#include <hip/hip_runtime.h>

// LSTMForecaster: B=2048, S=512, IN=1, H=64, OUT=72, 2 LSTM layers + FC.
// Round 3: MFMA (16x16x32 bf16) with split-float hi/lo for fp32 accuracy.
//  - 256 blocks x 512 threads (8 waves). Block owns 8 batch rows.
//  - Pipelined: iter k does layer0 gates @k and layer1 gates @k-1 in ONE GEMM:
//      A[16x128] = [h0(k-1) | h1(k-2)] (rows 8..15 padding),
//      B[128x512]: cols 0-255 = [Whh0 ; 0], cols 256-511 = [Wih1 ; Whh1].
//  - Weights permanently in B-fragments (registers). A via small LDS dbuf.
//  - Wave w: hid slice [16*(w&3), +16) of layer (w>>2), ALL 4 gates ->
//    state update fully in-lane, 1 barrier/iter.

#define BATCH 2048
#define SEQ   512
#define HIDN  64
#define NOUT  72
#define BT    8
#define NT    512

typedef __bf16 bf16x8 __attribute__((ext_vector_type(8)));
typedef float f32x4  __attribute__((ext_vector_type(4)));
typedef unsigned short us8 __attribute__((ext_vector_type(8)));

union CvtAB { us8 u; bf16x8 b; };

__device__ __forceinline__ float fast_rcp(float x){ return __builtin_amdgcn_rcpf(x); }
__device__ __forceinline__ float sigm(float x){ return fast_rcp(1.f + __expf(-x)); }
__device__ __forceinline__ float tanh_f(float x){ return 1.f - 2.f*fast_rcp(__expf(2.f*x)+1.f); }

__device__ __forceinline__ unsigned short bf16_rne(float v){
    unsigned u = __float_as_uint(v);
    return (unsigned short)((u + 0x7FFFu + ((u>>16)&1u)) >> 16);
}

__global__ __launch_bounds__(NT, 2)
void lstm2_mfma_kernel(const float* __restrict__ x,     // [B,S]
                       const float* __restrict__ wih0,  // [256,1]
                       const float* __restrict__ whh0,  // [256,64]
                       const float* __restrict__ bih0,
                       const float* __restrict__ bhh0,
                       const float* __restrict__ wih1,  // [256,64]
                       const float* __restrict__ whh1,  // [256,64]
                       const float* __restrict__ bih1,
                       const float* __restrict__ bhh1,
                       const float* __restrict__ fcw,   // [72,64]
                       const float* __restrict__ fcb,
                       float* __restrict__ out)         // [B,72]
{
    const int t    = threadIdx.x;
    const int lane = t & 63;
    const int w    = t >> 6;      // wave 0..7
    const int wq   = w & 3;       // hid-block within layer
    const int lyr  = w >> 2;      // 0 or 1
    const int l15  = lane & 15;
    const int lg   = lane >> 4;   // 0..3 (k lane-group)
    const int b0   = blockIdx.x * BT;
    const int hidb = wq * 16;

    __shared__ float x_sb[SEQ][BT];                      // 16 KB, [s][b]
    __shared__ unsigned short fragA[2][2][4][32][8];     // [buf][hi/lo][kc][slot][e] 8 KB
    __shared__ float h_fc[BT][HIDN + 1];                 // padded rows

    // ---- B-fragments (weights) into registers: [gate q][kc], hi and lo ----
    bf16x8 bh[4][4], bl[4][4];
    float  bsum[4], wx[4];
    #pragma unroll
    for (int q = 0; q < 4; ++q) {
        const int c = q*64 + hidb + l15;     // gate unit 0..255 within layer
        #pragma unroll
        for (int kc = 0; kc < 4; ++kc) {
            const float* src = nullptr;
            if (lyr == 0) {
                if (kc < 2) src = whh0 + c*HIDN + kc*32 + lg*8;   // k rows 0-63
                // kc 2,3: zero block (layer0 has K=64)
            } else {
                src = (kc < 2) ? (wih1 + c*HIDN + kc*32 + lg*8)
                               : (whh1 + c*HIDN + (kc-2)*32 + lg*8);
            }
            CvtAB hb, lb;
            #pragma unroll
            for (int e = 0; e < 8; ++e) {
                float v = src ? src[e] : 0.f;
                unsigned short hi = bf16_rne(v);
                float hif = __uint_as_float(((unsigned)hi) << 16);
                unsigned short lo = bf16_rne(v - hif);
                hb.u[e] = hi; lb.u[e] = lo;
            }
            bh[q][kc] = hb.b;
            bl[q][kc] = lb.b;
        }
        bsum[q] = lyr ? (bih1[c] + bhh1[c]) : (bih0[c] + bhh0[c]);
        wx[q]   = lyr ? 0.f : wih0[c];
    }

    // ---- stage x (transposed [s][b]); zero fragA double-buffer ----
    for (int i = t; i < BT * SEQ; i += NT) {
        int b = i >> 9, s = i & (SEQ - 1);
        x_sb[s][b] = x[(size_t)(b0 + b) * SEQ + s];
    }
    {
        unsigned* fz = (unsigned*)fragA;   // 2*2*4*32*8*2B = 8192B = 2048 dwords
        for (int i = t; i < 2048; i += NT) fz[i] = 0u;
    }
    __syncthreads();

    // cell state: lanes 0-31 hold c for rows b = 4*lg + r (r=0..3), hid hidb+l15
    float cst[4] = {0.f, 0.f, 0.f, 0.f};
    const int slot_rd = lg * 8 + (lane & 7);   // duplicated for (lane&15)>=8: harmless re-read
    const int hh  = hidb + l15;                // hid index this lane updates (lanes<32)
    const int kcs = lyr * 2 + (hh >> 5);       // fragA kc slot for our h writes
    const int eW  = hh & 7;
    const int g5  = (hh >> 3) & 3;

    #pragma unroll 1
    for (int k = 0; k <= SEQ; ++k) {
        const int buf = k & 1, nbuf = buf ^ 1;

        // ---- A-fragments from LDS ----
        bf16x8 ah[4], al[4];
        #pragma unroll
        for (int kc = 0; kc < 4; ++kc) {
            CvtAB ch, cl;
            ch.u = *(const us8*)&fragA[buf][0][kc][slot_rd][0];
            cl.u = *(const us8*)&fragA[buf][1][kc][slot_rd][0];
            ah[kc] = ch.b; al[kc] = cl.b;
        }

        // ---- GEMM: 48 MFMA (4 gate-tiles x 4 kc x 3 hi/lo terms) ----
        f32x4 acc[4];
        #pragma unroll
        for (int q = 0; q < 4; ++q) acc[q] = f32x4{0.f, 0.f, 0.f, 0.f};
        #pragma unroll
        for (int kc = 0; kc < 4; ++kc) {
            #pragma unroll
            for (int q = 0; q < 4; ++q) {
                acc[q] = __builtin_amdgcn_mfma_f32_16x16x32_bf16(ah[kc], bh[q][kc], acc[q], 0, 0, 0);
                acc[q] = __builtin_amdgcn_mfma_f32_16x16x32_bf16(al[kc], bh[q][kc], acc[q], 0, 0, 0);
                acc[q] = __builtin_amdgcn_mfma_f32_16x16x32_bf16(ah[kc], bl[q][kc], acc[q], 0, 0, 0);
            }
        }

        // ---- activation + state update, fully in-lane (lanes 0-31 = rows 0-7)
        const bool do_state = lyr ? (k > 0) : (k < SEQ);
        if (do_state && lane < 32) {
            float x4[4];
            if (lyr == 0) {
                const float* xp = &x_sb[k][lg * 4];
                #pragma unroll
                for (int r = 0; r < 4; ++r) x4[r] = xp[r];
            } else {
                #pragma unroll
                for (int r = 0; r < 4; ++r) x4[r] = 0.f;
            }
            #pragma unroll
            for (int r = 0; r < 4; ++r) {
                const int b = lg * 4 + r;          // batch row 0..7
                float pi = acc[0][r] + bsum[0] + wx[0] * x4[r];
                float pf = acc[1][r] + bsum[1] + wx[1] * x4[r];
                float pg = acc[2][r] + bsum[2] + wx[2] * x4[r];
                float po = acc[3][r] + bsum[3] + wx[3] * x4[r];
                float iv = sigm(pi), fv = sigm(pf), gv = tanh_f(pg), ov = sigm(po);
                cst[r] = fmaf(fv, cst[r], iv * gv);
                float h = ov * tanh_f(cst[r]);
                unsigned short hi = bf16_rne(h);
                float hif = __uint_as_float(((unsigned)hi) << 16);
                unsigned short lo = bf16_rne(h - hif);
                const int sl = g5 * 8 + b;
                fragA[nbuf][0][kcs][sl][eW] = hi;
                fragA[nbuf][1][kcs][sl][eW] = lo;
                if (lyr == 1 && k == SEQ) h_fc[b][hh] = h;   // h1(511) final
            }
        }
        __syncthreads();
    }

    // ---- FC: out = h1_final @ fc_w^T + fc_b ----
    for (int idx = t; idx < BT * NOUT; idx += NT) {
        int b = idx / NOUT, o = idx - b * NOUT;
        float a = fcb[o];
        #pragma unroll
        for (int j = 0; j < HIDN; ++j) a = fmaf(h_fc[b][j], fcw[o * HIDN + j], a);
        out[(size_t)(b0 + b) * NOUT + o] = a;
    }
}

extern "C" void kernel_launch(void* const* d_in, const int* in_sizes, int n_in,
                              void* d_out, int out_size, void* d_ws, size_t ws_size,
                              hipStream_t stream) {
    const float* x    = (const float*)d_in[0];
    const float* wih0 = (const float*)d_in[1];
    const float* whh0 = (const float*)d_in[2];
    const float* bih0 = (const float*)d_in[3];
    const float* bhh0 = (const float*)d_in[4];
    const float* wih1 = (const float*)d_in[5];
    const float* whh1 = (const float*)d_in[6];
    const float* bih1 = (const float*)d_in[7];
    const float* bhh1 = (const float*)d_in[8];
    const float* fcw  = (const float*)d_in[9];
    const float* fcb  = (const float*)d_in[10];
    float* out = (float*)d_out;

    dim3 grid(BATCH / BT);   // 256 blocks -> 1 per CU
    dim3 block(NT);
    hipLaunchKernelGGL(lstm2_mfma_kernel, grid, block, 0, stream,
                       x, wih0, whh0, bih0, bhh0, wih1, whh1, bih1, bhh1,
                       fcw, fcb, out);
}

// Round 5
// 491.307 us; speedup vs baseline: 9.3548x; 1.6899x over previous
//
#include <hip/hip_runtime.h>

// LSTMForecaster: B=2048, S=512, IN=1, H=64, OUT=72, 2 LSTM layers + FC.
// Round 4 (resubmit after infra timeout): fp16 MFMA, 2-term split
// (h = hi+lo fp16 = 22-bit; weights single fp16), layer-0 zero-K blocks
// skipped, bias in C-init, activations spread to all 64 lanes via
// v_permlane32_swap_b32.

#define BATCH 2048
#define SEQ   512
#define HIDN  64
#define NOUT  72
#define BT    8
#define NT    512

typedef _Float16 f16x8 __attribute__((ext_vector_type(8)));
typedef float    f32x4 __attribute__((ext_vector_type(4)));

__device__ __forceinline__ float fast_rcp(float x){ return __builtin_amdgcn_rcpf(x); }
__device__ __forceinline__ float sigm(float x){ return fast_rcp(1.f + __expf(-x)); }
__device__ __forceinline__ float tanh_f(float x){ return 1.f - 2.f*fast_rcp(__expf(2.f*x)+1.f); }

// after this: a = [a.lanes0-31 | b.lanes0-31]  (b clobbered)
__device__ __forceinline__ float swap_pick(float a, float b){
    unsigned ua = __float_as_uint(a), ub = __float_as_uint(b);
    asm volatile("v_permlane32_swap_b32 %0, %1" : "+v"(ua), "+v"(ub));
    return __uint_as_float(ua);
}

__global__ __launch_bounds__(NT, 2)
void lstm2_mfma_kernel(const float* __restrict__ x,     // [B,S]
                       const float* __restrict__ wih0,  // [256,1]
                       const float* __restrict__ whh0,  // [256,64]
                       const float* __restrict__ bih0,
                       const float* __restrict__ bhh0,
                       const float* __restrict__ wih1,  // [256,64]
                       const float* __restrict__ whh1,  // [256,64]
                       const float* __restrict__ bih1,
                       const float* __restrict__ bhh1,
                       const float* __restrict__ fcw,   // [72,64]
                       const float* __restrict__ fcb,
                       float* __restrict__ out)         // [B,72]
{
    const int t    = threadIdx.x;
    const int lane = t & 63;
    const int w    = t >> 6;      // wave 0..7
    const int wq   = w & 3;       // hid-block within layer
    const int lyr  = w >> 2;      // 0 or 1
    const int l15  = lane & 15;
    const int lg   = lane >> 4;   // 0..3
    const int b0   = blockIdx.x * BT;
    const int hidb = wq * 16;

    __shared__ float x_sb[SEQ][BT];                          // 16 KB [s][b]
    __shared__ __align__(16) _Float16 fragA[2][2][4][32][8]; // [buf][hi/lo][kc][slot][e] 8 KB
    __shared__ float h_fc[BT][HIDN + 1];

    // ---- B-fragments (weights) single fp16, registers ----
    f16x8 bw[4][4];
    float bsum[4], wx[4];
    #pragma unroll
    for (int q = 0; q < 4; ++q) {
        const int c = q*64 + hidb + l15;     // gate unit within layer
        if (lyr == 0) {
            #pragma unroll
            for (int kc = 0; kc < 2; ++kc) {
                const float* src = whh0 + c*HIDN + kc*32 + lg*8;
                f16x8 v;
                #pragma unroll
                for (int e = 0; e < 8; ++e) v[e] = (_Float16)src[e];
                bw[q][kc] = v;
            }
            bsum[q] = bih0[c] + bhh0[c];
            wx[q]   = wih0[c];
        } else {
            #pragma unroll
            for (int kc = 0; kc < 4; ++kc) {
                const float* src = (kc < 2) ? (wih1 + c*HIDN + kc*32 + lg*8)
                                            : (whh1 + c*HIDN + (kc-2)*32 + lg*8);
                f16x8 v;
                #pragma unroll
                for (int e = 0; e < 8; ++e) v[e] = (_Float16)src[e];
                bw[q][kc] = v;
            }
            bsum[q] = bih1[c] + bhh1[c];
            wx[q]   = 0.f;
        }
    }

    // ---- stage x (transposed [s][b]); zero fragA ----
    for (int i = t; i < BT * SEQ; i += NT) {
        int b = i >> 9, s = i & (SEQ - 1);
        x_sb[s][b] = x[(size_t)(b0 + b) * SEQ + s];
    }
    {
        unsigned* fz = (unsigned*)fragA;   // 8192 B = 2048 dwords
        for (int i = t; i < 2048; i += NT) fz[i] = 0u;
    }
    __syncthreads();

    // this lane's two state rows (after permlane spread):
    //  lanes 0-15: b 0,1 | 16-31: b 4,5 | 32-47: b 2,3 | 48-63: b 6,7
    const int bb   = ((lane >> 4) & 1) * 4 + (lane >> 5) * 2;
    const int hh   = hidb + l15;               // hid index this lane updates
    const int kcs  = lyr * 2 + (hh >> 5);      // fragA kc slot for h writes
    const int eW   = hh & 7;
    const int g5   = (hh >> 3) & 3;
    const int slot_rd = lg * 8 + (lane & 7);
    float c0 = 0.f, c1 = 0.f;                  // cell state for rows bb, bb+1

    #pragma unroll 1
    for (int k = 0; k <= SEQ; ++k) {
        const int buf = k & 1, nbuf = buf ^ 1;

        // ---- GEMM: C-init = bias; 2 terms (A hi + A lo) x single-fp16 B ----
        f32x4 acc[4];
        #pragma unroll
        for (int q = 0; q < 4; ++q) acc[q] = f32x4{bsum[q], bsum[q], bsum[q], bsum[q]};

        if (lyr == 0) {
            f16x8 ah[2], al[2];
            #pragma unroll
            for (int kc = 0; kc < 2; ++kc) {
                ah[kc] = *(const f16x8*)&fragA[buf][0][kc][slot_rd][0];
                al[kc] = *(const f16x8*)&fragA[buf][1][kc][slot_rd][0];
            }
            #pragma unroll
            for (int kc = 0; kc < 2; ++kc) {
                #pragma unroll
                for (int q = 0; q < 4; ++q) {
                    acc[q] = __builtin_amdgcn_mfma_f32_16x16x32_f16(ah[kc], bw[q][kc], acc[q], 0, 0, 0);
                    acc[q] = __builtin_amdgcn_mfma_f32_16x16x32_f16(al[kc], bw[q][kc], acc[q], 0, 0, 0);
                }
            }
        } else {
            f16x8 ah[4], al[4];
            #pragma unroll
            for (int kc = 0; kc < 4; ++kc) {
                ah[kc] = *(const f16x8*)&fragA[buf][0][kc][slot_rd][0];
                al[kc] = *(const f16x8*)&fragA[buf][1][kc][slot_rd][0];
            }
            #pragma unroll
            for (int kc = 0; kc < 4; ++kc) {
                #pragma unroll
                for (int q = 0; q < 4; ++q) {
                    acc[q] = __builtin_amdgcn_mfma_f32_16x16x32_f16(ah[kc], bw[q][kc], acc[q], 0, 0, 0);
                    acc[q] = __builtin_amdgcn_mfma_f32_16x16x32_f16(al[kc], bw[q][kc], acc[q], 0, 0, 0);
                }
            }
        }

        // ---- activation + state update, spread over all 64 lanes ----
        const bool do_state = lyr ? (k > 0) : (k < SEQ);
        if (do_state) {
            // ga = gates of row bb, gb = gates of row bb+1 (bias included)
            float ga[4], gb[4];
            #pragma unroll
            for (int q = 0; q < 4; ++q) {
                ga[q] = swap_pick(acc[q][0], acc[q][2]);
                gb[q] = swap_pick(acc[q][1], acc[q][3]);
            }
            float pia = ga[0], pfa = ga[1], pga = ga[2], poa = ga[3];
            float pib = gb[0], pfb = gb[1], pgb = gb[2], pob = gb[3];
            if (lyr == 0) {
                float xa = x_sb[k][bb], xb = x_sb[k][bb + 1];
                pia = fmaf(wx[0], xa, pia); pib = fmaf(wx[0], xb, pib);
                pfa = fmaf(wx[1], xa, pfa); pfb = fmaf(wx[1], xb, pfb);
                pga = fmaf(wx[2], xa, pga); pgb = fmaf(wx[2], xb, pgb);
                poa = fmaf(wx[3], xa, poa); pob = fmaf(wx[3], xb, pob);
            }
            // row A
            {
                float iv = sigm(pia), fv = sigm(pfa), gv = tanh_f(pga), ov = sigm(poa);
                c0 = fmaf(fv, c0, iv * gv);
                float h = ov * tanh_f(c0);
                _Float16 hi = (_Float16)h;
                _Float16 lo = (_Float16)(h - (float)hi);
                fragA[nbuf][0][kcs][g5*8 + bb][eW] = hi;
                fragA[nbuf][1][kcs][g5*8 + bb][eW] = lo;
                if (lyr == 1 && k == SEQ) h_fc[bb][hh] = h;
            }
            // row B
            {
                float iv = sigm(pib), fv = sigm(pfb), gv = tanh_f(pgb), ov = sigm(pob);
                c1 = fmaf(fv, c1, iv * gv);
                float h = ov * tanh_f(c1);
                _Float16 hi = (_Float16)h;
                _Float16 lo = (_Float16)(h - (float)hi);
                fragA[nbuf][0][kcs][g5*8 + bb + 1][eW] = hi;
                fragA[nbuf][1][kcs][g5*8 + bb + 1][eW] = lo;
                if (lyr == 1 && k == SEQ) h_fc[bb + 1][hh] = h;
            }
        }
        __syncthreads();
    }

    // ---- FC: out = h1_final @ fc_w^T + fc_b ----
    for (int idx = t; idx < BT * NOUT; idx += NT) {
        int b = idx / NOUT, o = idx - b * NOUT;
        float a = fcb[o];
        #pragma unroll
        for (int j = 0; j < HIDN; ++j) a = fmaf(h_fc[b][j], fcw[o * HIDN + j], a);
        out[(size_t)(b0 + b) * NOUT + o] = a;
    }
}

extern "C" void kernel_launch(void* const* d_in, const int* in_sizes, int n_in,
                              void* d_out, int out_size, void* d_ws, size_t ws_size,
                              hipStream_t stream) {
    const float* x    = (const float*)d_in[0];
    const float* wih0 = (const float*)d_in[1];
    const float* whh0 = (const float*)d_in[2];
    const float* bih0 = (const float*)d_in[3];
    const float* bhh0 = (const float*)d_in[4];
    const float* wih1 = (const float*)d_in[5];
    const float* whh1 = (const float*)d_in[6];
    const float* bih1 = (const float*)d_in[7];
    const float* bhh1 = (const float*)d_in[8];
    const float* fcw  = (const float*)d_in[9];
    const float* fcb  = (const float*)d_in[10];
    float* out = (float*)d_out;

    dim3 grid(BATCH / BT);   // 256 blocks -> 1 per CU
    dim3 block(NT);
    hipLaunchKernelGGL(lstm2_mfma_kernel, grid, block, 0, stream,
                       x, wih0, whh0, bih0, bhh0, wih1, whh1, bih1, bhh1,
                       fcw, fcb, out);
}

// Round 6
// 391.967 us; speedup vs baseline: 11.7256x; 1.2534x over previous
//
#include <hip/hip_runtime.h>

// LSTMForecaster: B=2048, S=512, IN=1, H=64, OUT=72, 2 LSTM layers + FC.
// Round 6: single-term fp16 MFMA (h stored as single fp16; weights fp16),
// exp2-direct activations (weights/biases pre-scaled by log2e, g-gate by
// 2*log2e, so sigmoid/tanh use raw v_exp_f32), layer-0 zero-K blocks skipped,
// bias in C-init, activations spread to all 64 lanes via v_permlane32_swap_b32.

#define BATCH 2048
#define SEQ   512
#define HIDN  64
#define NOUT  72
#define BT    8
#define NT    512
#define L2E   1.4426950408889634f

typedef _Float16 f16x8 __attribute__((ext_vector_type(8)));
typedef float    f32x4 __attribute__((ext_vector_type(4)));

__device__ __forceinline__ float fast_rcp(float x){ return __builtin_amdgcn_rcpf(x); }
__device__ __forceinline__ float exp2_hw(float x){ float r; asm("v_exp_f32 %0, %1" : "=v"(r) : "v"(x)); return r; }
__device__ __forceinline__ float exp2_neg_hw(float x){ float r; asm("v_exp_f32 %0, -%1" : "=v"(r) : "v"(x)); return r; }
// input pre-scaled by log2e: sigmoid(x) = 1/(1+2^-s)
__device__ __forceinline__ float sigm2(float s){ return fast_rcp(1.f + exp2_neg_hw(s)); }
// input pre-scaled by 2*log2e: tanh(x) = 1 - 2/(2^s+1)
__device__ __forceinline__ float tanh2(float s){ return fmaf(-2.f, fast_rcp(exp2_hw(s) + 1.f), 1.f); }

// after this: result = [a.lanes0-31 | b.lanes0-31]
__device__ __forceinline__ float swap_pick(float a, float b){
    unsigned ua = __float_as_uint(a), ub = __float_as_uint(b);
    asm volatile("v_permlane32_swap_b32 %0, %1" : "+v"(ua), "+v"(ub));
    return __uint_as_float(ua);
}

__global__ __launch_bounds__(NT, 2)
void lstm2_mfma_kernel(const float* __restrict__ x,     // [B,S]
                       const float* __restrict__ wih0,  // [256,1]
                       const float* __restrict__ whh0,  // [256,64]
                       const float* __restrict__ bih0,
                       const float* __restrict__ bhh0,
                       const float* __restrict__ wih1,  // [256,64]
                       const float* __restrict__ whh1,  // [256,64]
                       const float* __restrict__ bih1,
                       const float* __restrict__ bhh1,
                       const float* __restrict__ fcw,   // [72,64]
                       const float* __restrict__ fcb,
                       float* __restrict__ out)         // [B,72]
{
    const int t    = threadIdx.x;
    const int lane = t & 63;
    const int w    = t >> 6;      // wave 0..7
    const int wq   = w & 3;       // hid-block within layer
    const int lyr  = w >> 2;      // 0 or 1
    const int l15  = lane & 15;
    const int lg   = lane >> 4;   // 0..3
    const int b0   = blockIdx.x * BT;
    const int hidb = wq * 16;

    __shared__ float x_sb[SEQ][BT];                       // 16 KB [s][b]
    __shared__ __align__(16) _Float16 fragA[2][4][32][8]; // [buf][kc][slot][e] 4 KB
    __shared__ float h_fc[BT][HIDN + 1];

    // ---- B-fragments (weights) single fp16, pre-scaled by gate scale ----
    //  gates i,f,o scaled by log2e; gate g (tanh) by 2*log2e.
    f16x8 bw[4][4];
    float bsum[4], wx[4];
    #pragma unroll
    for (int q = 0; q < 4; ++q) {
        const float sc = (q == 2) ? (2.f * L2E) : L2E;
        const int c = q*64 + hidb + l15;     // gate unit within layer
        if (lyr == 0) {
            #pragma unroll
            for (int kc = 0; kc < 2; ++kc) {
                const float* src = whh0 + c*HIDN + kc*32 + lg*8;
                f16x8 v;
                #pragma unroll
                for (int e = 0; e < 8; ++e) v[e] = (_Float16)(src[e] * sc);
                bw[q][kc] = v;
            }
            bsum[q] = (bih0[c] + bhh0[c]) * sc;
            wx[q]   = wih0[c] * sc;
        } else {
            #pragma unroll
            for (int kc = 0; kc < 4; ++kc) {
                const float* src = (kc < 2) ? (wih1 + c*HIDN + kc*32 + lg*8)
                                            : (whh1 + c*HIDN + (kc-2)*32 + lg*8);
                f16x8 v;
                #pragma unroll
                for (int e = 0; e < 8; ++e) v[e] = (_Float16)(src[e] * sc);
                bw[q][kc] = v;
            }
            bsum[q] = (bih1[c] + bhh1[c]) * sc;
            wx[q]   = 0.f;
        }
    }

    // ---- stage x (transposed [s][b]); zero fragA ----
    for (int i = t; i < BT * SEQ; i += NT) {
        int b = i >> 9, s = i & (SEQ - 1);
        x_sb[s][b] = x[(size_t)(b0 + b) * SEQ + s];
    }
    {
        unsigned* fz = (unsigned*)fragA;   // 4096 B = 1024 dwords
        for (int i = t; i < 1024; i += NT) fz[i] = 0u;
    }
    __syncthreads();

    // lane's two state rows after permlane spread:
    //  lanes 0-15: b 0,1 | 16-31: b 4,5 | 32-47: b 2,3 | 48-63: b 6,7
    const int bb   = ((lane >> 4) & 1) * 4 + (lane >> 5) * 2;
    const int hh   = hidb + l15;               // hid index this lane updates
    const int kcs  = lyr * 2 + (hh >> 5);      // fragA kc slot for h writes
    const int eW   = hh & 7;
    const int g5   = (hh >> 3) & 3;
    const int slot_rd = lg * 8 + (lane & 7);
    float c0 = 0.f, c1 = 0.f;                  // cell state rows bb, bb+1

    #pragma unroll 1
    for (int k = 0; k <= SEQ; ++k) {
        const int buf = k & 1, nbuf = buf ^ 1;

        // ---- GEMM: C-init = scaled bias; single fp16 term ----
        f32x4 acc[4];
        #pragma unroll
        for (int q = 0; q < 4; ++q) acc[q] = f32x4{bsum[q], bsum[q], bsum[q], bsum[q]};

        if (lyr == 0) {
            f16x8 a0 = *(const f16x8*)&fragA[buf][0][slot_rd][0];
            f16x8 a1 = *(const f16x8*)&fragA[buf][1][slot_rd][0];
            #pragma unroll
            for (int q = 0; q < 4; ++q) {
                acc[q] = __builtin_amdgcn_mfma_f32_16x16x32_f16(a0, bw[q][0], acc[q], 0, 0, 0);
                acc[q] = __builtin_amdgcn_mfma_f32_16x16x32_f16(a1, bw[q][1], acc[q], 0, 0, 0);
            }
        } else {
            f16x8 a[4];
            #pragma unroll
            for (int kc = 0; kc < 4; ++kc)
                a[kc] = *(const f16x8*)&fragA[buf][kc][slot_rd][0];
            #pragma unroll
            for (int kc = 0; kc < 4; ++kc) {
                #pragma unroll
                for (int q = 0; q < 4; ++q)
                    acc[q] = __builtin_amdgcn_mfma_f32_16x16x32_f16(a[kc], bw[q][kc], acc[q], 0, 0, 0);
            }
        }

        // ---- activation + state update, spread over all 64 lanes ----
        const bool do_state = lyr ? (k > 0) : (k < SEQ);
        if (do_state) {
            float ga[4], gb[4];
            #pragma unroll
            for (int q = 0; q < 4; ++q) {
                ga[q] = swap_pick(acc[q][0], acc[q][2]);
                gb[q] = swap_pick(acc[q][1], acc[q][3]);
            }
            float pia = ga[0], pfa = ga[1], pga = ga[2], poa = ga[3];
            float pib = gb[0], pfb = gb[1], pgb = gb[2], pob = gb[3];
            if (lyr == 0) {
                float xa = x_sb[k][bb], xb = x_sb[k][bb + 1];
                pia = fmaf(wx[0], xa, pia); pib = fmaf(wx[0], xb, pib);
                pfa = fmaf(wx[1], xa, pfa); pfb = fmaf(wx[1], xb, pfb);
                pga = fmaf(wx[2], xa, pga); pgb = fmaf(wx[2], xb, pgb);
                poa = fmaf(wx[3], xa, poa); pob = fmaf(wx[3], xb, pob);
            }
            // row A
            {
                float iv = sigm2(pia), fv = sigm2(pfa), gv = tanh2(pga), ov = sigm2(poa);
                c0 = fmaf(fv, c0, iv * gv);
                float h = ov * tanh2(c0 * (2.f * L2E));
                fragA[nbuf][kcs][g5*8 + bb][eW] = (_Float16)h;
                if (lyr == 1 && k == SEQ) h_fc[bb][hh] = h;
            }
            // row B
            {
                float iv = sigm2(pib), fv = sigm2(pfb), gv = tanh2(pgb), ov = sigm2(pob);
                c1 = fmaf(fv, c1, iv * gv);
                float h = ov * tanh2(c1 * (2.f * L2E));
                fragA[nbuf][kcs][g5*8 + bb + 1][eW] = (_Float16)h;
                if (lyr == 1 && k == SEQ) h_fc[bb + 1][hh] = h;
            }
        }
        __syncthreads();
    }

    // ---- FC: out = h1_final @ fc_w^T + fc_b ----
    for (int idx = t; idx < BT * NOUT; idx += NT) {
        int b = idx / NOUT, o = idx - b * NOUT;
        float a = fcb[o];
        #pragma unroll
        for (int j = 0; j < HIDN; ++j) a = fmaf(h_fc[b][j], fcw[o * HIDN + j], a);
        out[(size_t)(b0 + b) * NOUT + o] = a;
    }
}

extern "C" void kernel_launch(void* const* d_in, const int* in_sizes, int n_in,
                              void* d_out, int out_size, void* d_ws, size_t ws_size,
                              hipStream_t stream) {
    const float* x    = (const float*)d_in[0];
    const float* wih0 = (const float*)d_in[1];
    const float* whh0 = (const float*)d_in[2];
    const float* bih0 = (const float*)d_in[3];
    const float* bhh0 = (const float*)d_in[4];
    const float* wih1 = (const float*)d_in[5];
    const float* whh1 = (const float*)d_in[6];
    const float* bih1 = (const float*)d_in[7];
    const float* bhh1 = (const float*)d_in[8];
    const float* fcw  = (const float*)d_in[9];
    const float* fcb  = (const float*)d_in[10];
    float* out = (float*)d_out;

    dim3 grid(BATCH / BT);   // 256 blocks -> 1 per CU
    dim3 block(NT);
    hipLaunchKernelGGL(lstm2_mfma_kernel, grid, block, 0, stream,
                       x, wih0, whh0, bih0, bhh0, wih1, whh1, bih1, bhh1,
                       fcw, fcb, out);
}